// Round 2
// baseline (362.595 us; speedup 1.0000x reference)
//
#include <hip/hip_runtime.h>

// ---------------------------------------------------------------------------
// LinearAttention (Taylor feature map), MI355X/gfx950.
// Inputs: FLOAT32 (runtime-probed; bf16 copies in ws). Outputs: FLOAT32
// [out (4,2048,1024) | kv_state (4,16,1,64,273)].
//
// qf.kf = 1 + (q.k)/4 + (q.k)^2/32 -> attention needs only S=QK^T.
// kv_state is a GEMM: KV[f,dd] = sum_n V^T[f,n] KF[n,dd].
//
// r8b: attn rewritten barrier-free. K/V^T fragments read directly from
// global (L2-resident; was LDS-staged behind 2 barriers/chunk). Only Ps
// (wave-private) stays in LDS -> 18.4 KB, no __syncthreads at all.
// v_cvt_pk_bf16_f32 replaces manual f2bf in the phi path; causal mask
// compiled out of non-diagonal chunks. Complementary task pairing
// (63-g, g) -> uniform 17 chunk-units per wave, grid (8,64); bijective
// XCD swizzle keeps each XCD's L2 on 8 bh of K/V.
// (fix vs r8: mask tags moved to namespace scope — local structs can't
// have static constexpr members.)
// ---------------------------------------------------------------------------

typedef unsigned short u16;
typedef __attribute__((ext_vector_type(4))) float f32x4;
typedef __attribute__((ext_vector_type(8))) short s16x8;

struct MaskT { static constexpr bool value = true;  };
struct MaskF { static constexpr bool value = false; };

__device__ __forceinline__ float bf2f(u16 u) {
    union { unsigned int i; float f; } x; x.i = ((unsigned int)u) << 16; return x.f;
}
__device__ __forceinline__ u16 f2bf(float f) {
    union { float f; unsigned int u; } x; x.f = f;
    unsigned int r = x.u + 0x7FFFu + ((x.u >> 16) & 1u);
    return (u16)(r >> 16);
}

// ---------------- input dtype probe + convert -------------------------------
__global__ void detect_kernel(const unsigned int* __restrict__ H, int* __restrict__ flag)
{
    const int lane = threadIdx.x;
    int cnt = 0;
#pragma unroll
    for (int i = 0; i < 16; ++i) {
        const unsigned int wrd = H[lane * 16 + i];
        const int e = (int)((wrd >> 7) & 0xFFu);
        if (e >= 85 && e <= 170) ++cnt;
    }
    cnt += __shfl_xor(cnt, 1);  cnt += __shfl_xor(cnt, 2);
    cnt += __shfl_xor(cnt, 4);  cnt += __shfl_xor(cnt, 8);
    cnt += __shfl_xor(cnt, 16); cnt += __shfl_xor(cnt, 32);
    if (lane == 0) *flag = (cnt < 700) ? 1 : 0;    // 1 = inputs are f32
}

__global__ __launch_bounds__(256)
void cvt_kernel(const void* __restrict__ src, u16* __restrict__ dst, int n,
                const int* __restrict__ flag)
{
    const int i = blockIdx.x * 256 + threadIdx.x;
    if (i >= n) return;
    if (*flag) dst[i] = f2bf(((const float*)src)[i]);
    else       dst[i] = ((const u16*)src)[i];
}

// ---------------- GEMM: C = A(8192,1024) . B(N,1024)^T, bf16 in, f32 acc ----
// MODE 0: fused QKV (N=1536): q,k head-interleaved bf16; V -> vt [b,h,64,l].
// MODE 1: N=1024, FLOAT32 row-major output Of.
template<int MODE>
__global__ __launch_bounds__(256)
void gemm_nt(const u16* __restrict__ A,
             const u16* __restrict__ Bq, const u16* __restrict__ Bk,
             const u16* __restrict__ Bv,
             u16* __restrict__ Oq, u16* __restrict__ Ok,
             u16* __restrict__ Ovt, float* __restrict__ Of)
{
    __shared__ __attribute__((aligned(16))) u16 As[128][40];
    __shared__ __attribute__((aligned(16))) u16 Bs[128][40];
    const int t = threadIdx.x;
    const int lane = t & 63, w = t >> 6;
    const int c = lane & 15, qd = lane >> 4;
    const int wm = (w >> 1) * 64, wn = (w & 1) * 64;
    const int rm = blockIdx.y * 128;
    const int cb = blockIdx.x * 128;

    const u16* Bsrc; int wrow0;
    if (MODE == 0) {
        if (cb < 256)      { Bsrc = Bq; wrow0 = cb; }
        else if (cb < 512) { Bsrc = Bk; wrow0 = cb - 256; }
        else               { Bsrc = Bv; wrow0 = cb - 512; }
    } else { Bsrc = Bq; wrow0 = cb; }

    f32x4 acc[4][4];
#pragma unroll
    for (int i = 0; i < 4; ++i)
#pragma unroll
        for (int j = 0; j < 4; ++j) acc[i][j] = (f32x4){0.f, 0.f, 0.f, 0.f};

    const int r0 = t >> 2, s0 = t & 3;
    const u16* Ap = A    + (size_t)(rm    + r0) * 1024 + s0 * 8;
    const u16* Bp = Bsrc + (size_t)(wrow0 + r0) * 1024 + s0 * 8;

    for (int kt = 0; kt < 32; ++kt) {
        const int k0 = kt * 32;
        uint4 a0 = *(const uint4*)(Ap + k0);
        uint4 a1 = *(const uint4*)(Ap + 64 * 1024 + k0);
        uint4 b0 = *(const uint4*)(Bp + k0);
        uint4 b1 = *(const uint4*)(Bp + 64 * 1024 + k0);
        __syncthreads();
        *(uint4*)&As[r0][s0 * 8]      = a0;
        *(uint4*)&As[r0 + 64][s0 * 8] = a1;
        *(uint4*)&Bs[r0][s0 * 8]      = b0;
        *(uint4*)&Bs[r0 + 64][s0 * 8] = b1;
        __syncthreads();
        s16x8 af[4], bfr[4];
#pragma unroll
        for (int mt = 0; mt < 4; ++mt) af[mt]  = *(const s16x8*)&As[wm + mt * 16 + c][qd * 8];
#pragma unroll
        for (int nt = 0; nt < 4; ++nt) bfr[nt] = *(const s16x8*)&Bs[wn + nt * 16 + c][qd * 8];
#pragma unroll
        for (int mt = 0; mt < 4; ++mt)
#pragma unroll
            for (int nt = 0; nt < 4; ++nt)
                acc[mt][nt] = __builtin_amdgcn_mfma_f32_16x16x32_bf16(af[mt], bfr[nt], acc[mt][nt], 0, 0, 0);
    }

#pragma unroll
    for (int mt = 0; mt < 4; ++mt) {
#pragma unroll
        for (int nt = 0; nt < 4; ++nt) {
            const int gc = cb + wn + nt * 16 + c;
            const int row0 = rm + wm + mt * 16 + qd * 4;
            if (MODE == 1) {
#pragma unroll
                for (int r = 0; r < 4; ++r)
                    Of[(size_t)(row0 + r) * 1024 + gc] = acc[mt][nt][r];
            } else if (gc < 512) {
#pragma unroll
                for (int r = 0; r < 4; ++r) {
                    const int row = row0 + r;
                    const int b_ = row >> 11, l_ = row & 2047;
                    const int cc = gc & 255;
                    const int h = cc >> 4, idx = cc & 15;
                    u16* dst = (gc < 256) ? Oq : Ok;
                    dst[(size_t)((b_ * 16 + h) * 2048 + l_) * 16 + idx] = f2bf(acc[mt][nt][r]);
                }
            } else {
                // V -> vt [b,h,64,l], r-consecutive => packed b64 store
                const int cc = gc - 512;
                const int h = cc >> 6, idx = cc & 63;
                const int b_ = row0 >> 11, l0 = row0 & 2047;
                ushort4 pk;
                pk.x = f2bf(acc[mt][nt][0]);
                pk.y = f2bf(acc[mt][nt][1]);
                pk.z = f2bf(acc[mt][nt][2]);
                pk.w = f2bf(acc[mt][nt][3]);
                *(ushort4*)(Ovt + ((size_t)((b_ * 16 + h) * 64 + idx)) * 2048 + l0) = pk;
            }
        }
    }
}

// ---------------- causal phi-attention, UNNORMALIZED y ----------------------
// Barrier-free. grid (8,64), 256 thr. Wave w owns complementary task pair
// (63-g, g), g = xblk*4+w: each task = 32 queries -> uniform 17 chunk-units
// per wave. Per 128-key chunk, two 64-key halves: S^T = mfma(K-frag from
// global, Q regs) -> phi (2 FMA + v_cvt_pk_bf16_f32) -> wave-private Ps ->
// PV = mfma(Ps rows, V^T frags from global vt). No __syncthreads. LDS 18.4KB.
__global__ __launch_bounds__(256, 4)
void attn_kernel(const u16* __restrict__ Qg, const u16* __restrict__ Kg,
                 const u16* __restrict__ Vt, u16* __restrict__ Yg)
{
    __shared__ __attribute__((aligned(16))) u16 Ps[128][72];
    const int t = threadIdx.x, lane = t & 63, w = t >> 6;
    const int c = lane & 15, qd = lane >> 4;
    // bijective XCD swizzle: 512 blocks, 8 XCDs -> XCD k serves bh [8k,8k+8)
    const int pid = blockIdx.y * 8 + blockIdx.x;
    const int lid = (pid & 7) * 64 + (pid >> 3);
    const int bh = lid >> 3;
    const int g  = (lid & 7) * 4 + w;            // 0..31
    const u16* Qh = Qg + (size_t)bh * (2048 * 16);
    const u16* Kh = Kg + (size_t)bh * (2048 * 16);
    const u16* Vh = Vt + (size_t)bh * (64 * 2048);
    const int qloc0 = w * 32;                    // wave-private Ps row base
    const f32x4 zacc = {0.f, 0.f, 0.f, 0.f};

    for (int pass = 0; pass < 2; ++pass) {
        const int task = pass ? g : (63 - g);    // query group of 32
        const int q0  = task * 32;
        const int nch = task >> 2;               // # fully-unmasked 128-chunks
        const int tp  = task & 3;                // position within diag chunk

        s16x8 bq[2];
#pragma unroll
        for (int mt = 0; mt < 2; ++mt) {
            s16x8 tmp = {0, 0, 0, 0, 0, 0, 0, 0};
            if (qd < 2)
                tmp = *(const s16x8*)(Qh + (size_t)(q0 + mt * 16 + c) * 16 + qd * 8);
            bq[mt] = tmp;
        }

        f32x4 yt[2][4];
#pragma unroll
        for (int mt = 0; mt < 2; ++mt)
#pragma unroll
            for (int ft = 0; ft < 4; ++ft) yt[mt][ft] = zacc;

        auto do_half = [&](int n0, int k0, auto MASKED) {
            constexpr bool masked = decltype(MASKED)::value;
            // S^T: A = K rows (keys) direct from global, B = Q regs
            f32x4 s[4][2];
#pragma unroll
            for (int at = 0; at < 4; ++at) {
                s16x8 ka = {0, 0, 0, 0, 0, 0, 0, 0};
                if (qd < 2)
                    ka = *(const s16x8*)(Kh + (size_t)(n0 + k0 + at * 16 + c) * 16 + qd * 8);
#pragma unroll
                for (int mt = 0; mt < 2; ++mt)
                    s[at][mt] = __builtin_amdgcn_mfma_f32_16x16x32_bf16(ka, bq[mt], zacc, 0, 0, 0);
            }
            // V^T fragments direct from vt [b,h,64,l] — issue before phi so
            // L2 latency hides under the VALU work
            s16x8 vb[2][4];
#pragma unroll
            for (int kt = 0; kt < 2; ++kt)
#pragma unroll
                for (int ft = 0; ft < 4; ++ft)
                    vb[kt][ft] = *(const s16x8*)(Vh + (size_t)(ft * 16 + c) * 2048
                                                 + n0 + k0 + kt * 32 + qd * 8);
            // phi + (diag-only) causal mask + packed b64 write to private Ps
#pragma unroll
            for (int at = 0; at < 4; ++at)
#pragma unroll
                for (int mt = 0; mt < 2; ++mt) {
                    float p[4];
#pragma unroll
                    for (int r = 0; r < 4; ++r) {
                        const float sv = s[at][mt][r];
                        float pv = fmaf(sv, fmaf(sv, 0.03125f, 0.25f), 1.0f);
                        if (masked && (k0 + at * 16 + qd * 4 + r) > (tp * 32 + mt * 16 + c))
                            pv = 0.f;
                        p[r] = pv;
                    }
                    uint2 pk;
                    asm("v_cvt_pk_bf16_f32 %0, %1, %2" : "=v"(pk.x) : "v"(p[0]), "v"(p[1]));
                    asm("v_cvt_pk_bf16_f32 %0, %1, %2" : "=v"(pk.y) : "v"(p[2]), "v"(p[3]));
                    *(uint2*)&Ps[qloc0 + mt * 16 + c][at * 16 + qd * 4] = pk;
                }
            // PV: y[q][f] += P . V  (A = own Ps rows, B = V^T regs)
#pragma unroll
            for (int kt = 0; kt < 2; ++kt) {
                s16x8 pa[2];
#pragma unroll
                for (int mt = 0; mt < 2; ++mt)
                    pa[mt] = *(const s16x8*)&Ps[qloc0 + mt * 16 + c][kt * 32 + qd * 8];
#pragma unroll
                for (int mt = 0; mt < 2; ++mt)
#pragma unroll
                    for (int ft = 0; ft < 4; ++ft)
                        yt[mt][ft] = __builtin_amdgcn_mfma_f32_16x16x32_bf16(
                            pa[mt], vb[kt][ft], yt[mt][ft], 0, 0, 0);
            }
        };

        for (int kc = 0; kc < nch; ++kc) {
            do_half(kc * 128, 0, MaskF{});
            do_half(kc * 128, 64, MaskF{});
        }
        {   // diagonal chunk: tp>=2 -> half0 fully unmasked, half1 masked;
            // tp<2  -> half0 masked, half1 fully above the diagonal (skip)
            const int n0 = nch * 128;
            if (tp >= 2) { do_half(n0, 0, MaskF{}); do_half(n0, 64, MaskT{}); }
            else         { do_half(n0, 0, MaskT{}); }
        }

        // store UNNORMALIZED y [b,h,l,64] bf16
#pragma unroll
        for (int mt = 0; mt < 2; ++mt) {
#pragma unroll
            for (int r = 0; r < 4; ++r) {
                const int i = q0 + mt * 16 + qd * 4 + r;
                u16* dst = Yg + ((size_t)bh * 2048 + i) * 64;
#pragma unroll
                for (int ft = 0; ft < 4; ++ft)
                    dst[ft * 16 + c] = f2bf(yt[mt][ft][r]);
            }
        }
    }
}

// ---------------- standalone RMSNorm: y [b,h,l,64] -> yn [b,l,1024] ---------
__global__ __launch_bounds__(256)
void rms_kernel(const u16* __restrict__ Yg, const u16* __restrict__ gw,
                u16* __restrict__ Yn)
{
    const int t = threadIdx.x, lane = t & 63, wv = t >> 6;
    const int row = blockIdx.x * 4 + wv;           // row = (b*16+h)*2048 + l
    const float v = bf2f(Yg[(size_t)row * 64 + lane]);
    float ss = v * v;
    ss += __shfl_xor(ss, 1);  ss += __shfl_xor(ss, 2);
    ss += __shfl_xor(ss, 4);  ss += __shfl_xor(ss, 8);
    ss += __shfl_xor(ss, 16); ss += __shfl_xor(ss, 32);
    const float rms = rsqrtf(ss * (1.0f / 64.0f) + 1e-5f);
    const int bh = row >> 11, l = row & 2047;
    const int b_ = bh >> 4, h_ = bh & 15;
    Yn[((size_t)(b_ * 2048 + l)) * 1024 + h_ * 64 + lane] =
        f2bf(v * rms * bf2f(gw[lane]));
}

// ---------------- kv_state as MFMA GEMM -------------------------------------
__global__ __launch_bounds__(256)
void kv_mfma_kernel(const u16* __restrict__ Kg, const u16* __restrict__ Vt,
                    float* __restrict__ kvpart)
{
    __shared__ __attribute__((aligned(16))) float kS[64][20];
    __shared__ __attribute__((aligned(16))) float kT[64][20];
    __shared__ __attribute__((aligned(16))) u16 KFs[288][72];
    __shared__ __attribute__((aligned(16))) u16 Vs[64][72];
    const int t = threadIdx.x, lane = t & 63, w = t >> 6;
    const int c = lane & 15, qd = lane >> 4;
    const int ns = blockIdx.x, bh = blockIdx.y;
    const u16* Kh  = Kg + (size_t)bh * 2048 * 16;
    const u16* Vth = Vt + (size_t)bh * 64 * 2048;

    int i2a, j2a, i2b = 18, j2b = 18;
    {
        const int dd = t;
        if (dd == 0)      { i2a = 16; j2a = 17; }
        else if (dd < 17) { i2a = dd - 1; j2a = 16; }
        else              { i2a = (dd - 17) >> 4; j2a = (dd - 17) & 15; }
        if (t < 32) {
            const int d2 = 256 + t;
            if (d2 < 273) { i2b = (d2 - 17) >> 4; j2b = (d2 - 17) & 15; }
        }
    }

    f32x4 acc[4][5];
#pragma unroll
    for (int mt = 0; mt < 4; ++mt)
#pragma unroll
        for (int j = 0; j < 5; ++j) acc[mt][j] = (f32x4){0.f, 0.f, 0.f, 0.f};

    for (int ch = 0; ch < 16; ++ch) {
        const int n0 = ns * 1024 + ch * 64;
        __syncthreads();
        if (t < 128) {
            const int row = t >> 1, half = t & 1;
            uint4 kv = *(const uint4*)(Kh + (size_t)(n0 + row) * 16 + half * 8);
            const u16* ke = (const u16*)&kv;
#pragma unroll
            for (int e = 0; e < 8; ++e) {
                const float f = bf2f(ke[e]);
                kS[row][half * 8 + e] = f;
                kT[row][half * 8 + e] = f * 0.17677669529663687f;
            }
        } else if (t < 192) {
            const int row = t - 128;
            kS[row][16] = 1.f;  kS[row][17] = 1.f;  kS[row][18] = 0.f;
            kT[row][16] = 0.5f; kT[row][17] = 1.f;  kT[row][18] = 0.f;
        }
        // stage V^T from vt: conflict-free b128
#pragma unroll
        for (int i = 0; i < 2; ++i) {
            const int lin = i * 256 + t;
            const int f = lin >> 3, seg = lin & 7;
            *(uint4*)&Vs[f][seg * 8] =
                *(const uint4*)(Vth + (size_t)f * 2048 + n0 + seg * 8);
        }
        __syncthreads();
        {
            unsigned int* dst = (unsigned int*)&KFs[t][0];
#pragma unroll 8
            for (int i = 0; i < 32; ++i) {
                const float v0 = kS[2 * i][i2a]     * kT[2 * i][j2a];
                const float v1 = kS[2 * i + 1][i2a] * kT[2 * i + 1][j2a];
                dst[i] = (unsigned int)f2bf(v0) | ((unsigned int)f2bf(v1) << 16);
            }
            if (t < 32) {
                unsigned int* dst2 = (unsigned int*)&KFs[256 + t][0];
#pragma unroll 8
                for (int i = 0; i < 32; ++i) {
                    const float v0 = kS[2 * i][i2b]     * kT[2 * i][j2b];
                    const float v1 = kS[2 * i + 1][i2b] * kT[2 * i + 1][j2b];
                    dst2[i] = (unsigned int)f2bf(v0) | ((unsigned int)f2bf(v1) << 16);
                }
            }
        }
        __syncthreads();
#pragma unroll
        for (int kt = 0; kt < 2; ++kt) {
            s16x8 va[4];
#pragma unroll
            for (int mt = 0; mt < 4; ++mt)
                va[mt] = *(const s16x8*)&Vs[mt * 16 + c][kt * 32 + qd * 8];
#pragma unroll
            for (int j = 0; j < 5; ++j) {
                const int dt = w + 4 * j;
                if (dt < 18) {
                    s16x8 vb = *(const s16x8*)&KFs[dt * 16 + c][kt * 32 + qd * 8];
#pragma unroll
                    for (int mt = 0; mt < 4; ++mt)
                        acc[mt][j] = __builtin_amdgcn_mfma_f32_16x16x32_bf16(va[mt], vb, acc[mt][j], 0, 0, 0);
                }
            }
        }
    }

    float* base = kvpart + ((size_t)(ns * 64 + bh) * 64) * 273;
#pragma unroll
    for (int j = 0; j < 5; ++j) {
        const int dt = w + 4 * j;
        if (dt >= 18) continue;
        const int dd = dt * 16 + c;
        if (dd >= 273) continue;
#pragma unroll
        for (int mt = 0; mt < 4; ++mt)
#pragma unroll
            for (int r = 0; r < 4; ++r) {
                const int f = mt * 16 + qd * 4 + r;
                base[f * 273 + dd] = acc[mt][j][r];
            }
    }
}

__global__ __launch_bounds__(256)
void kv_fin_kernel(const float* __restrict__ kvpart, float* __restrict__ o)
{
    const int i = blockIdx.x * 256 + threadIdx.x;
    if (i < 64 * 64 * 273) o[i] = kvpart[i] + kvpart[i + 64 * 64 * 273];
}

// ---------------------------------------------------------------------------
extern "C" void kernel_launch(void* const* d_in, const int* in_sizes, int n_in,
                              void* d_out, int out_size, void* d_ws, size_t ws_size,
                              hipStream_t stream)
{
    const void* H  = d_in[0];
    const void* Wq = d_in[1];
    const void* Wk = d_in[2];
    const void* Wv = d_in[3];
    const void* Wo = d_in[4];
    const void* gw = d_in[5];
    float* outf = (float*)d_out;

    char* ws = (char*)d_ws;
    const size_t M = 1 << 20;
    u16*   Hb    = (u16*)(ws);                          // 16 MiB (reused as yn)
    u16*   Wqb   = (u16*)(ws + 16 * M);
    u16*   Wkb   = (u16*)(ws + 16 * M + 512 * 1024);
    u16*   Wvb   = (u16*)(ws + 17 * M);
    u16*   Wob   = (u16*)(ws + 19 * M);
    u16*   gwb   = (u16*)(ws + 21 * M);
    int*   flag  = (int*)(ws + 21 * M + 4096);
    u16*   q     = (u16*)(ws + 22 * M);                 // 4 MiB
    u16*   k     = (u16*)(ws + 26 * M);                 // 4 MiB
    u16*   vt    = (u16*)(ws + 30 * M);                 // 16 MiB [b,h,64,l]
    u16*   y     = (u16*)(ws + 46 * M);                 // 16 MiB [b,h,l,64]
    float* kvpart= (float*)(ws + 62 * M);               // 2 x 4.26 MiB
    u16*   yn    = Hb;                                  // reuse after gemm0

    detect_kernel<<<1, 64, 0, stream>>>((const unsigned int*)H, flag);
    cvt_kernel<<<(in_sizes[0] + 255) / 256, 256, 0, stream>>>(H,  Hb,  in_sizes[0], flag);
    cvt_kernel<<<(in_sizes[1] + 255) / 256, 256, 0, stream>>>(Wq, Wqb, in_sizes[1], flag);
    cvt_kernel<<<(in_sizes[2] + 255) / 256, 256, 0, stream>>>(Wk, Wkb, in_sizes[2], flag);
    cvt_kernel<<<(in_sizes[3] + 255) / 256, 256, 0, stream>>>(Wv, Wvb, in_sizes[3], flag);
    cvt_kernel<<<(in_sizes[4] + 255) / 256, 256, 0, stream>>>(Wo, Wob, in_sizes[4], flag);
    cvt_kernel<<<1, 256, 0, stream>>>(gw, gwb, in_sizes[5], flag);

    gemm_nt<0><<<dim3(12, 64), 256, 0, stream>>>(Hb, Wqb, Wkb, Wvb, q, k, vt, nullptr);
    attn_kernel<<<dim3(8, 64), 256, 0, stream>>>(q, k, vt, y);
    rms_kernel<<<32768, 256, 0, stream>>>(y, gwb, yn);
    kv_mfma_kernel<<<dim3(2, 64), 256, 0, stream>>>(k, vt, kvpart);
    kv_fin_kernel<<<4368, 256, 0, stream>>>(kvpart, outf + (size_t)8388608);
    gemm_nt<1><<<dim3(8, 64), 256, 0, stream>>>(yn, Wob, nullptr, nullptr,
                                                nullptr, nullptr, nullptr, outf);
}

// Round 3
// 307.420 us; speedup vs baseline: 1.1795x; 1.1795x over previous
//
#include <hip/hip_runtime.h>

// ---------------------------------------------------------------------------
// LinearAttention (Taylor feature map), MI355X/gfx950.
// Inputs: FLOAT32 (runtime-probed; bf16 copies in ws). Outputs: FLOAT32
// [out (4,2048,1024) | kv_state (4,16,1,64,273)].
//
// qf.kf = 1 + (q.k)/4 + (q.k)^2/32 -> attention needs only S=QK^T.
// kv_state is a GEMM: KV[f,dd] = sum_n V^T[f,n] KF[n,dd].
//
// r9: (1) attn: key-half split -> 2 waves per task pair, grid (16,64) =
// 4 blocks/CU = 16 waves/CU (2x TLP; r8b was latency-bound at 8 waves/CU).
// Partial y summed via wave-pair LDS exchange (unioned with Ps region);
// RMSNorm fused into the attn epilogue (rms_kernel + y buffer eliminated).
// (2) gemm_nt: global_load_lds width-16 staging into linear LDS (m97
// structure, ~874 TF class vs ~500 for reg-staging). (3) kv_mfma: 4-way
// key split, grid (4,64) = full GPU; kv_fin sums 4 slabs.
// ---------------------------------------------------------------------------

typedef unsigned short u16;
typedef unsigned int u32;
typedef __attribute__((ext_vector_type(4))) float f32x4;
typedef __attribute__((ext_vector_type(8))) short s16x8;

struct MaskT { static constexpr bool value = true;  };
struct MaskF { static constexpr bool value = false; };

__device__ __forceinline__ float bf2f(u16 u) {
    union { unsigned int i; float f; } x; x.i = ((unsigned int)u) << 16; return x.f;
}
__device__ __forceinline__ u16 f2bf(float f) {
    union { float f; unsigned int u; } x; x.f = f;
    unsigned int r = x.u + 0x7FFFu + ((x.u >> 16) & 1u);
    return (u16)(r >> 16);
}

typedef const __attribute__((address_space(1))) u32* gas1_t;
typedef __attribute__((address_space(3))) u32* las3_t;
__device__ __forceinline__ void gld16(const u16* g, u16* l) {
    __builtin_amdgcn_global_load_lds((gas1_t)(const void*)g, (las3_t)(void*)l, 16, 0, 0);
}

// ---------------- input dtype probe + convert -------------------------------
__global__ void detect_kernel(const unsigned int* __restrict__ H, int* __restrict__ flag)
{
    const int lane = threadIdx.x;
    int cnt = 0;
#pragma unroll
    for (int i = 0; i < 16; ++i) {
        const unsigned int wrd = H[lane * 16 + i];
        const int e = (int)((wrd >> 7) & 0xFFu);
        if (e >= 85 && e <= 170) ++cnt;
    }
    cnt += __shfl_xor(cnt, 1);  cnt += __shfl_xor(cnt, 2);
    cnt += __shfl_xor(cnt, 4);  cnt += __shfl_xor(cnt, 8);
    cnt += __shfl_xor(cnt, 16); cnt += __shfl_xor(cnt, 32);
    if (lane == 0) *flag = (cnt < 700) ? 1 : 0;    // 1 = inputs are f32
}

__global__ __launch_bounds__(256)
void cvt_kernel(const void* __restrict__ src, u16* __restrict__ dst, int n,
                const int* __restrict__ flag)
{
    const int i = blockIdx.x * 256 + threadIdx.x;
    if (i >= n) return;
    if (*flag) dst[i] = f2bf(((const float*)src)[i]);
    else       dst[i] = ((const u16*)src)[i];
}

// ---------------- GEMM: C = A(8192,1024) . B(N,1024)^T, bf16 in, f32 acc ----
// m97 structure: global_load_lds width=16 into linear LDS [128][32], BK=32,
// 2 barriers per K-step. MODE 0: fused QKV (N=1536); MODE 1: N=1024 f32 out.
template<int MODE>
__global__ __launch_bounds__(256)
void gemm_nt(const u16* __restrict__ A,
             const u16* __restrict__ Bq, const u16* __restrict__ Bk,
             const u16* __restrict__ Bv,
             u16* __restrict__ Oq, u16* __restrict__ Ok,
             u16* __restrict__ Ovt, float* __restrict__ Of)
{
    __shared__ __attribute__((aligned(16))) u16 As[4096];   // 128 x 32, linear
    __shared__ __attribute__((aligned(16))) u16 Bs[4096];
    const int t = threadIdx.x;
    const int lane = t & 63, w = t >> 6;
    const int c = lane & 15, qd = lane >> 4;
    const int wm = (w >> 1) * 64, wn = (w & 1) * 64;
    const int rm = blockIdx.y * 128;
    const int cb = blockIdx.x * 128;

    const u16* Bsrc; int wrow0;
    if (MODE == 0) {
        if (cb < 256)      { Bsrc = Bq; wrow0 = cb; }
        else if (cb < 512) { Bsrc = Bk; wrow0 = cb - 256; }
        else               { Bsrc = Bv; wrow0 = cb - 512; }
    } else { Bsrc = Bq; wrow0 = cb; }

    f32x4 acc[4][4];
#pragma unroll
    for (int i = 0; i < 4; ++i)
#pragma unroll
        for (int j = 0; j < 4; ++j) acc[i][j] = (f32x4){0.f, 0.f, 0.f, 0.f};

    // staging addresses: thread t covers (row = t>>2 [+64], 16B-seg = t&3)
    const u16* Ag = A    + (size_t)(rm    + (t >> 2)) * 1024 + (t & 3) * 8;
    const u16* Bg = Bsrc + (size_t)(wrow0 + (t >> 2)) * 1024 + (t & 3) * 8;
    u16* AsW = As + w * 512;   // wave-uniform LDS dest base (lane*16B added by HW)
    u16* BsW = Bs + w * 512;

    for (int kt = 0; kt < 32; ++kt) {
        const int k0 = kt * 32;
        __syncthreads();                        // prior readers done
        gld16(Ag + k0,         AsW);
        gld16(Ag + 65536 + k0, AsW + 2048);     // rows +64 -> LDS +4096B
        gld16(Bg + k0,         BsW);
        gld16(Bg + 65536 + k0, BsW + 2048);
        __syncthreads();                        // drains vmcnt, joins waves
        s16x8 af[4], bfr[4];
#pragma unroll
        for (int mt = 0; mt < 4; ++mt) af[mt]  = *(const s16x8*)&As[(wm + mt * 16 + c) * 32 + qd * 8];
#pragma unroll
        for (int nt = 0; nt < 4; ++nt) bfr[nt] = *(const s16x8*)&Bs[(wn + nt * 16 + c) * 32 + qd * 8];
#pragma unroll
        for (int mt = 0; mt < 4; ++mt)
#pragma unroll
            for (int nt = 0; nt < 4; ++nt)
                acc[mt][nt] = __builtin_amdgcn_mfma_f32_16x16x32_bf16(af[mt], bfr[nt], acc[mt][nt], 0, 0, 0);
    }

#pragma unroll
    for (int mt = 0; mt < 4; ++mt) {
#pragma unroll
        for (int nt = 0; nt < 4; ++nt) {
            const int gc = cb + wn + nt * 16 + c;
            const int row0 = rm + wm + mt * 16 + qd * 4;
            if (MODE == 1) {
#pragma unroll
                for (int r = 0; r < 4; ++r)
                    Of[(size_t)(row0 + r) * 1024 + gc] = acc[mt][nt][r];
            } else if (gc < 512) {
#pragma unroll
                for (int r = 0; r < 4; ++r) {
                    const int row = row0 + r;
                    const int b_ = row >> 11, l_ = row & 2047;
                    const int cc = gc & 255;
                    const int h = cc >> 4, idx = cc & 15;
                    u16* dst = (gc < 256) ? Oq : Ok;
                    dst[(size_t)((b_ * 16 + h) * 2048 + l_) * 16 + idx] = f2bf(acc[mt][nt][r]);
                }
            } else {
                // V -> vt [b,h,64,l], r-consecutive => packed b64 store
                const int cc = gc - 512;
                const int h = cc >> 6, idx = cc & 63;
                const int b_ = row0 >> 11, l0 = row0 & 2047;
                ushort4 pk;
                pk.x = f2bf(acc[mt][nt][0]);
                pk.y = f2bf(acc[mt][nt][1]);
                pk.z = f2bf(acc[mt][nt][2]);
                pk.w = f2bf(acc[mt][nt][3]);
                *(ushort4*)(Ovt + ((size_t)((b_ * 16 + h) * 64 + idx)) * 2048 + l0) = pk;
            }
        }
    }
}

// ---------------- causal phi-attention + fused RMSNorm ----------------------
// grid (16,64), 256 thr. Block = 2 task pairs; each pair = 2 waves split by
// key-half parity (wave h handles k0 = h*64 of every 128-chunk). Each wave
// computes partial y for both tasks of its pair; per pass, wave pair sums
// partials via LDS exchange (region unioned with wave-private Ps), then
// computes RMSNorm and writes yn [b,l,1024] bf16 directly.
__global__ __launch_bounds__(256, 4)
void attn_kernel(const u16* __restrict__ Qg, const u16* __restrict__ Kg,
                 const u16* __restrict__ Vt, const u16* __restrict__ gwb,
                 u16* __restrict__ Yn)
{
    __shared__ __attribute__((aligned(16))) char ldsbuf[4][8192];  // per-wave: Ps / exchange
    const int t = threadIdx.x, lane = t & 63, w = t >> 6;
    const int c = lane & 15, qd = lane >> 4;
    // bijective XCD swizzle: 1024 blocks, 8 XCDs -> XCD x serves bh [8x,8x+8)
    const int pid = blockIdx.y * 16 + blockIdx.x;
    const int lid = (pid & 7) * 128 + (pid >> 3);
    const int bh = lid >> 4;
    const int pr = (lid & 15) * 2 + (w >> 1);    // pair 0..31
    const int h  = w & 1;                        // key-half
    const int b_ = bh >> 4, hh = bh & 15;
    const u16* Qh = Qg + (size_t)bh * (2048 * 16);
    const u16* Kh = Kg + (size_t)bh * (2048 * 16);
    const u16* Vh = Vt + (size_t)bh * (64 * 2048);
    u16 (*Ps)[72]     = reinterpret_cast<u16(*)[72]>(&ldsbuf[w][0]);
    float* exw        = reinterpret_cast<float*>(&ldsbuf[w][0]);
    const float* exq  = reinterpret_cast<const float*>(&ldsbuf[w ^ 1][0]);
    const f32x4 zacc = {0.f, 0.f, 0.f, 0.f};
    float gl[4];
#pragma unroll
    for (int ft = 0; ft < 4; ++ft) gl[ft] = bf2f(gwb[ft * 16 + c]);

    for (int pass = 0; pass < 2; ++pass) {
        const int task = pass ? pr : (63 - pr);  // query group of 32
        const int q0  = task * 32;
        const int nch = task >> 2;               // # fully-unmasked 128-chunks
        const int tp  = task & 3;                // position within diag chunk

        s16x8 bq[2];
#pragma unroll
        for (int mt = 0; mt < 2; ++mt) {
            s16x8 tmp = {0, 0, 0, 0, 0, 0, 0, 0};
            if (qd < 2)
                tmp = *(const s16x8*)(Qh + (size_t)(q0 + mt * 16 + c) * 16 + qd * 8);
            bq[mt] = tmp;
        }

        f32x4 yt[2][4];
#pragma unroll
        for (int mt = 0; mt < 2; ++mt)
#pragma unroll
            for (int ft = 0; ft < 4; ++ft) yt[mt][ft] = zacc;

        auto do_half = [&](int n0, int k0, auto MASKED) {
            constexpr bool masked = decltype(MASKED)::value;
            const int nb = n0 + k0;
            // K fragments (issue first; QK waits only on these)
            s16x8 ka[4];
#pragma unroll
            for (int at = 0; at < 4; ++at) {
                s16x8 tmp = {0, 0, 0, 0, 0, 0, 0, 0};
                if (qd < 2)
                    tmp = *(const s16x8*)(Kh + (size_t)(nb + at * 16 + c) * 16 + qd * 8);
                ka[at] = tmp;
            }
            // V^T fragments: issue now, latency hides under QK+phi
            s16x8 vb[2][4];
#pragma unroll
            for (int kt = 0; kt < 2; ++kt)
#pragma unroll
                for (int ft = 0; ft < 4; ++ft)
                    vb[kt][ft] = *(const s16x8*)(Vh + (size_t)(ft * 16 + c) * 2048
                                                 + nb + kt * 32 + qd * 8);
            // per-at: QK^T -> phi -> packed b64 write into wave-private Ps
#pragma unroll
            for (int at = 0; at < 4; ++at) {
                f32x4 sv[2];
                sv[0] = __builtin_amdgcn_mfma_f32_16x16x32_bf16(ka[at], bq[0], zacc, 0, 0, 0);
                sv[1] = __builtin_amdgcn_mfma_f32_16x16x32_bf16(ka[at], bq[1], zacc, 0, 0, 0);
#pragma unroll
                for (int mt = 0; mt < 2; ++mt) {
                    float p[4];
#pragma unroll
                    for (int r = 0; r < 4; ++r) {
                        const float s = sv[mt][r];
                        float pv = fmaf(s, fmaf(s, 0.03125f, 0.25f), 1.0f);
                        if (masked && (k0 + at * 16 + qd * 4 + r) > (tp * 32 + mt * 16 + c))
                            pv = 0.f;
                        p[r] = pv;
                    }
                    uint2 pk;
                    asm("v_cvt_pk_bf16_f32 %0, %1, %2" : "=v"(pk.x) : "v"(p[0]), "v"(p[1]));
                    asm("v_cvt_pk_bf16_f32 %0, %1, %2" : "=v"(pk.y) : "v"(p[2]), "v"(p[3]));
                    *(uint2*)&Ps[mt * 16 + c][at * 16 + qd * 4] = pk;
                }
            }
            // PV: y[q][f] += P . V
#pragma unroll
            for (int kt = 0; kt < 2; ++kt) {
                s16x8 pa[2];
#pragma unroll
                for (int mt = 0; mt < 2; ++mt)
                    pa[mt] = *(const s16x8*)&Ps[mt * 16 + c][kt * 32 + qd * 8];
#pragma unroll
                for (int mt = 0; mt < 2; ++mt)
#pragma unroll
                    for (int ft = 0; ft < 4; ++ft)
                        yt[mt][ft] = __builtin_amdgcn_mfma_f32_16x16x32_bf16(
                            pa[mt], vb[kt][ft], yt[mt][ft], 0, 0, 0);
            }
        };

        for (int kc = 0; kc < nch; ++kc) do_half(kc * 128, h * 64, MaskF{});
        if (tp >= 2) {
            if (h == 0) do_half(nch * 128, 0,  MaskF{});
            else        do_half(nch * 128, 64, MaskT{});
        } else if (h == 0) {
            do_half(nch * 128, 0, MaskT{});
        }

        // ---- wave-pair exchange (partner's half of keys) + fused RMSNorm ----
        __syncthreads();     // all compute done; ex regions (== Ps) free
        if (h == 0) {
#pragma unroll
            for (int ft = 0; ft < 4; ++ft)
                *(f32x4*)(exw + ft * 256 + lane * 4) = yt[1][ft];   // partner owns mt=1
        } else {
#pragma unroll
            for (int ft = 0; ft < 4; ++ft)
                *(f32x4*)(exw + ft * 256 + lane * 4) = yt[0][ft];   // partner owns mt=0
        }
        __syncthreads();     // partials visible
        f32x4 ysh[4];
        if (h == 0) {
#pragma unroll
            for (int ft = 0; ft < 4; ++ft)
                ysh[ft] = yt[0][ft] + *(const f32x4*)(exq + ft * 256 + lane * 4);
        } else {
#pragma unroll
            for (int ft = 0; ft < 4; ++ft)
                ysh[ft] = yt[1][ft] + *(const f32x4*)(exq + ft * 256 + lane * 4);
        }
        __syncthreads();     // partner read done; region reusable as Ps next pass

        // RMSNorm over f (=64) for this wave's 16 rows, write yn [b,l,1024]
#pragma unroll
        for (int r = 0; r < 4; ++r) {
            float ss = ysh[0][r] * ysh[0][r] + ysh[1][r] * ysh[1][r]
                     + ysh[2][r] * ysh[2][r] + ysh[3][r] * ysh[3][r];
            ss += __shfl_xor(ss, 1); ss += __shfl_xor(ss, 2);
            ss += __shfl_xor(ss, 4); ss += __shfl_xor(ss, 8);
            const float rmsv = rsqrtf(ss * (1.0f / 64.0f) + 1e-5f);
            const int row = q0 + h * 16 + qd * 4 + r;
            u16* dst = Yn + ((size_t)(b_ * 2048 + row)) * 1024 + hh * 64;
#pragma unroll
            for (int ft = 0; ft < 4; ++ft)
                dst[ft * 16 + c] = f2bf(ysh[ft][r] * rmsv * gl[ft]);
        }
    }
}

// ---------------- kv_state as MFMA GEMM -------------------------------------
// grid (4,64): 4-way key split -> 256 blocks (full GPU). Each block: 8 chunks.
__global__ __launch_bounds__(256)
void kv_mfma_kernel(const u16* __restrict__ Kg, const u16* __restrict__ Vt,
                    float* __restrict__ kvpart)
{
    __shared__ __attribute__((aligned(16))) float kS[64][20];
    __shared__ __attribute__((aligned(16))) float kT[64][20];
    __shared__ __attribute__((aligned(16))) u16 KFs[288][72];
    __shared__ __attribute__((aligned(16))) u16 Vs[64][72];
    const int t = threadIdx.x, lane = t & 63, w = t >> 6;
    const int c = lane & 15, qd = lane >> 4;
    const int ns = blockIdx.x, bh = blockIdx.y;
    const u16* Kh  = Kg + (size_t)bh * 2048 * 16;
    const u16* Vth = Vt + (size_t)bh * 64 * 2048;

    int i2a, j2a, i2b = 18, j2b = 18;
    {
        const int dd = t;
        if (dd == 0)      { i2a = 16; j2a = 17; }
        else if (dd < 17) { i2a = dd - 1; j2a = 16; }
        else              { i2a = (dd - 17) >> 4; j2a = (dd - 17) & 15; }
        if (t < 32) {
            const int d2 = 256 + t;
            if (d2 < 273) { i2b = (d2 - 17) >> 4; j2b = (d2 - 17) & 15; }
        }
    }

    f32x4 acc[4][5];
#pragma unroll
    for (int mt = 0; mt < 4; ++mt)
#pragma unroll
        for (int j = 0; j < 5; ++j) acc[mt][j] = (f32x4){0.f, 0.f, 0.f, 0.f};

    for (int ch = 0; ch < 8; ++ch) {
        const int n0 = ns * 512 + ch * 64;
        __syncthreads();
        if (t < 128) {
            const int row = t >> 1, half = t & 1;
            uint4 kv = *(const uint4*)(Kh + (size_t)(n0 + row) * 16 + half * 8);
            const u16* ke = (const u16*)&kv;
#pragma unroll
            for (int e = 0; e < 8; ++e) {
                const float f = bf2f(ke[e]);
                kS[row][half * 8 + e] = f;
                kT[row][half * 8 + e] = f * 0.17677669529663687f;
            }
        } else if (t < 192) {
            const int row = t - 128;
            kS[row][16] = 1.f;  kS[row][17] = 1.f;  kS[row][18] = 0.f;
            kT[row][16] = 0.5f; kT[row][17] = 1.f;  kT[row][18] = 0.f;
        }
        // stage V^T from vt: conflict-free b128
#pragma unroll
        for (int i = 0; i < 2; ++i) {
            const int lin = i * 256 + t;
            const int f = lin >> 3, seg = lin & 7;
            *(uint4*)&Vs[f][seg * 8] =
                *(const uint4*)(Vth + (size_t)f * 2048 + n0 + seg * 8);
        }
        __syncthreads();
        {
            unsigned int* dst = (unsigned int*)&KFs[t][0];
#pragma unroll 8
            for (int i = 0; i < 32; ++i) {
                const float v0 = kS[2 * i][i2a]     * kT[2 * i][j2a];
                const float v1 = kS[2 * i + 1][i2a] * kT[2 * i + 1][j2a];
                dst[i] = (unsigned int)f2bf(v0) | ((unsigned int)f2bf(v1) << 16);
            }
            if (t < 32) {
                unsigned int* dst2 = (unsigned int*)&KFs[256 + t][0];
#pragma unroll 8
                for (int i = 0; i < 32; ++i) {
                    const float v0 = kS[2 * i][i2b]     * kT[2 * i][j2b];
                    const float v1 = kS[2 * i + 1][i2b] * kT[2 * i + 1][j2b];
                    dst2[i] = (unsigned int)f2bf(v0) | ((unsigned int)f2bf(v1) << 16);
                }
            }
        }
        __syncthreads();
#pragma unroll
        for (int kt = 0; kt < 2; ++kt) {
            s16x8 va[4];
#pragma unroll
            for (int mt = 0; mt < 4; ++mt)
                va[mt] = *(const s16x8*)&Vs[mt * 16 + c][kt * 32 + qd * 8];
#pragma unroll
            for (int j = 0; j < 5; ++j) {
                const int dt = w + 4 * j;
                if (dt < 18) {
                    s16x8 vb = *(const s16x8*)&KFs[dt * 16 + c][kt * 32 + qd * 8];
#pragma unroll
                    for (int mt = 0; mt < 4; ++mt)
                        acc[mt][j] = __builtin_amdgcn_mfma_f32_16x16x32_bf16(va[mt], vb, acc[mt][j], 0, 0, 0);
                }
            }
        }
    }

    float* base = kvpart + ((size_t)(ns * 64 + bh) * 64) * 273;
#pragma unroll
    for (int j = 0; j < 5; ++j) {
        const int dt = w + 4 * j;
        if (dt >= 18) continue;
        const int dd = dt * 16 + c;
        if (dd >= 273) continue;
#pragma unroll
        for (int mt = 0; mt < 4; ++mt)
#pragma unroll
            for (int r = 0; r < 4; ++r) {
                const int f = mt * 16 + qd * 4 + r;
                base[f * 273 + dd] = acc[mt][j][r];
            }
    }
}

__global__ __launch_bounds__(256)
void kv_fin_kernel(const float* __restrict__ kvpart, float* __restrict__ o)
{
    const int i = blockIdx.x * 256 + threadIdx.x;
    const int S = 64 * 64 * 273;
    if (i < S)
        o[i] = kvpart[i] + kvpart[i + S] + kvpart[i + 2 * S] + kvpart[i + 3 * S];
}

// ---------------------------------------------------------------------------
extern "C" void kernel_launch(void* const* d_in, const int* in_sizes, int n_in,
                              void* d_out, int out_size, void* d_ws, size_t ws_size,
                              hipStream_t stream)
{
    const void* H  = d_in[0];
    const void* Wq = d_in[1];
    const void* Wk = d_in[2];
    const void* Wv = d_in[3];
    const void* Wo = d_in[4];
    const void* gw = d_in[5];
    float* outf = (float*)d_out;

    char* ws = (char*)d_ws;
    const size_t M = 1 << 20;
    u16*   Hb    = (u16*)(ws);                          // 16 MiB (reused as yn)
    u16*   Wqb   = (u16*)(ws + 16 * M);
    u16*   Wkb   = (u16*)(ws + 16 * M + 512 * 1024);
    u16*   Wvb   = (u16*)(ws + 17 * M);
    u16*   Wob   = (u16*)(ws + 19 * M);
    u16*   gwb   = (u16*)(ws + 21 * M);
    int*   flag  = (int*)(ws + 21 * M + 4096);
    u16*   q     = (u16*)(ws + 22 * M);                 // 4 MiB
    u16*   k     = (u16*)(ws + 26 * M);                 // 4 MiB
    u16*   vt    = (u16*)(ws + 30 * M);                 // 16 MiB [b,h,64,l]
    float* kvpart= (float*)(ws + 46 * M);               // 4 x 4.27 MiB slabs
    u16*   yn    = Hb;                                  // reuse after gemm0

    detect_kernel<<<1, 64, 0, stream>>>((const unsigned int*)H, flag);
    cvt_kernel<<<(in_sizes[0] + 255) / 256, 256, 0, stream>>>(H,  Hb,  in_sizes[0], flag);
    cvt_kernel<<<(in_sizes[1] + 255) / 256, 256, 0, stream>>>(Wq, Wqb, in_sizes[1], flag);
    cvt_kernel<<<(in_sizes[2] + 255) / 256, 256, 0, stream>>>(Wk, Wkb, in_sizes[2], flag);
    cvt_kernel<<<(in_sizes[3] + 255) / 256, 256, 0, stream>>>(Wv, Wvb, in_sizes[3], flag);
    cvt_kernel<<<(in_sizes[4] + 255) / 256, 256, 0, stream>>>(Wo, Wob, in_sizes[4], flag);
    cvt_kernel<<<1, 256, 0, stream>>>(gw, gwb, in_sizes[5], flag);

    gemm_nt<0><<<dim3(12, 64), 256, 0, stream>>>(Hb, Wqb, Wkb, Wvb, q, k, vt, nullptr);
    attn_kernel<<<dim3(16, 64), 256, 0, stream>>>(q, k, vt, gwb, yn);
    kv_mfma_kernel<<<dim3(4, 64), 256, 0, stream>>>(k, vt, kvpart);
    kv_fin_kernel<<<4368, 256, 0, stream>>>(kvpart, outf + (size_t)8388608);
    gemm_nt<1><<<dim3(8, 64), 256, 0, stream>>>(yn, Wob, nullptr, nullptr,
                                                nullptr, nullptr, nullptr, outf);
}

// Round 4
// 257.652 us; speedup vs baseline: 1.4073x; 1.1932x over previous
//
#include <hip/hip_runtime.h>

// ---------------------------------------------------------------------------
// LinearAttention (Taylor feature map), MI355X/gfx950.
// Inputs: FLOAT32 (runtime-probed; bf16 copies in ws). Outputs: FLOAT32
// [out (4,2048,1024) | kv_state (4,16,1,64,273)].
//
// qf.kf = 1 + (q.k)/4 + (q.k)^2/32 -> attention needs only S=QK^T.
// kv_state is a GEMM: KV[f,dd] = sum_n V^T[f,n] KF[n,dd].
//
// r10: attn rebuilt on 32x32x16 MFMA (K=16 == FEATURE_DIM; no zero-padded
// halves, all frag loads dense). P stays fully in-register: S^T C-layout ->
// PV A-layout via v_cvt_pk_bf16_f32 + v_permlane32_swap_b32 (no Ps LDS).
// V staged per 512-thr block (8 waves share) via global_load_lds with
// pre-swizzled source -> conflict-free swizzled ds_read_b128; double-buffered,
// 1 barrier/chunk, K prefetch in regs. Block = 256 queries, pair (7-j, j)
// -> 18 chunks/block constant; grid (4,64), XCD-swizzled. RMSNorm fused.
// ---------------------------------------------------------------------------

typedef unsigned short u16;
typedef unsigned int u32;
typedef __attribute__((ext_vector_type(4))) float f32x4;
typedef __attribute__((ext_vector_type(16))) float f32x16;
typedef __attribute__((ext_vector_type(8))) short s16x8;

struct MaskT { static constexpr bool value = true;  };
struct MaskF { static constexpr bool value = false; };

__device__ __forceinline__ float bf2f(u16 u) {
    union { unsigned int i; float f; } x; x.i = ((unsigned int)u) << 16; return x.f;
}
__device__ __forceinline__ u16 f2bf(float f) {
    union { float f; unsigned int u; } x; x.f = f;
    unsigned int r = x.u + 0x7FFFu + ((x.u >> 16) & 1u);
    return (u16)(r >> 16);
}

typedef const __attribute__((address_space(1))) u32* gas1_t;
typedef __attribute__((address_space(3))) u32* las3_t;
__device__ __forceinline__ void gld16(const u16* g, u16* l) {
    __builtin_amdgcn_global_load_lds((gas1_t)(const void*)g, (las3_t)(void*)l, 16, 0, 0);
}

// ---------------- input dtype probe + convert -------------------------------
__global__ void detect_kernel(const unsigned int* __restrict__ H, int* __restrict__ flag)
{
    const int lane = threadIdx.x;
    int cnt = 0;
#pragma unroll
    for (int i = 0; i < 16; ++i) {
        const unsigned int wrd = H[lane * 16 + i];
        const int e = (int)((wrd >> 7) & 0xFFu);
        if (e >= 85 && e <= 170) ++cnt;
    }
    cnt += __shfl_xor(cnt, 1);  cnt += __shfl_xor(cnt, 2);
    cnt += __shfl_xor(cnt, 4);  cnt += __shfl_xor(cnt, 8);
    cnt += __shfl_xor(cnt, 16); cnt += __shfl_xor(cnt, 32);
    if (lane == 0) *flag = (cnt < 700) ? 1 : 0;    // 1 = inputs are f32
}

__global__ __launch_bounds__(256)
void cvt_kernel(const void* __restrict__ src, u16* __restrict__ dst, int n,
                const int* __restrict__ flag)
{
    const int i = blockIdx.x * 256 + threadIdx.x;
    if (i >= n) return;
    if (*flag) dst[i] = f2bf(((const float*)src)[i]);
    else       dst[i] = ((const u16*)src)[i];
}

// ---------------- GEMM: C = A(8192,1024) . B(N,1024)^T, bf16 in, f32 acc ----
// m97 structure: global_load_lds width=16 into linear LDS [128][32], BK=32,
// 2 barriers per K-step. MODE 0: fused QKV (N=1536); MODE 1: N=1024 f32 out.
template<int MODE>
__global__ __launch_bounds__(256)
void gemm_nt(const u16* __restrict__ A,
             const u16* __restrict__ Bq, const u16* __restrict__ Bk,
             const u16* __restrict__ Bv,
             u16* __restrict__ Oq, u16* __restrict__ Ok,
             u16* __restrict__ Ovt, float* __restrict__ Of)
{
    __shared__ __attribute__((aligned(16))) u16 As[4096];   // 128 x 32, linear
    __shared__ __attribute__((aligned(16))) u16 Bs[4096];
    const int t = threadIdx.x;
    const int lane = t & 63, w = t >> 6;
    const int c = lane & 15, qd = lane >> 4;
    const int wm = (w >> 1) * 64, wn = (w & 1) * 64;
    const int rm = blockIdx.y * 128;
    const int cb = blockIdx.x * 128;

    const u16* Bsrc; int wrow0;
    if (MODE == 0) {
        if (cb < 256)      { Bsrc = Bq; wrow0 = cb; }
        else if (cb < 512) { Bsrc = Bk; wrow0 = cb - 256; }
        else               { Bsrc = Bv; wrow0 = cb - 512; }
    } else { Bsrc = Bq; wrow0 = cb; }

    f32x4 acc[4][4];
#pragma unroll
    for (int i = 0; i < 4; ++i)
#pragma unroll
        for (int j = 0; j < 4; ++j) acc[i][j] = (f32x4){0.f, 0.f, 0.f, 0.f};

    // staging addresses: thread t covers (row = t>>2 [+64], 16B-seg = t&3)
    const u16* Ag = A    + (size_t)(rm    + (t >> 2)) * 1024 + (t & 3) * 8;
    const u16* Bg = Bsrc + (size_t)(wrow0 + (t >> 2)) * 1024 + (t & 3) * 8;
    u16* AsW = As + w * 512;   // wave-uniform LDS dest base (lane*16B added by HW)
    u16* BsW = Bs + w * 512;

    for (int kt = 0; kt < 32; ++kt) {
        const int k0 = kt * 32;
        __syncthreads();                        // prior readers done
        gld16(Ag + k0,         AsW);
        gld16(Ag + 65536 + k0, AsW + 2048);     // rows +64 -> LDS +4096B
        gld16(Bg + k0,         BsW);
        gld16(Bg + 65536 + k0, BsW + 2048);
        __syncthreads();                        // drains vmcnt, joins waves
        s16x8 af[4], bfr[4];
#pragma unroll
        for (int mt = 0; mt < 4; ++mt) af[mt]  = *(const s16x8*)&As[(wm + mt * 16 + c) * 32 + qd * 8];
#pragma unroll
        for (int nt = 0; nt < 4; ++nt) bfr[nt] = *(const s16x8*)&Bs[(wn + nt * 16 + c) * 32 + qd * 8];
#pragma unroll
        for (int mt = 0; mt < 4; ++mt)
#pragma unroll
            for (int nt = 0; nt < 4; ++nt)
                acc[mt][nt] = __builtin_amdgcn_mfma_f32_16x16x32_bf16(af[mt], bfr[nt], acc[mt][nt], 0, 0, 0);
    }

#pragma unroll
    for (int mt = 0; mt < 4; ++mt) {
#pragma unroll
        for (int nt = 0; nt < 4; ++nt) {
            const int gc = cb + wn + nt * 16 + c;
            const int row0 = rm + wm + mt * 16 + qd * 4;
            if (MODE == 1) {
#pragma unroll
                for (int r = 0; r < 4; ++r)
                    Of[(size_t)(row0 + r) * 1024 + gc] = acc[mt][nt][r];
            } else if (gc < 512) {
#pragma unroll
                for (int r = 0; r < 4; ++r) {
                    const int row = row0 + r;
                    const int b_ = row >> 11, l_ = row & 2047;
                    const int cc = gc & 255;
                    const int h = cc >> 4, idx = cc & 15;
                    u16* dst = (gc < 256) ? Oq : Ok;
                    dst[(size_t)((b_ * 16 + h) * 2048 + l_) * 16 + idx] = f2bf(acc[mt][nt][r]);
                }
            } else {
                // V -> vt [b,h,64,l], r-consecutive => packed b64 store
                const int cc = gc - 512;
                const int h = cc >> 6, idx = cc & 63;
                const int b_ = row0 >> 11, l0 = row0 & 2047;
                ushort4 pk;
                pk.x = f2bf(acc[mt][nt][0]);
                pk.y = f2bf(acc[mt][nt][1]);
                pk.z = f2bf(acc[mt][nt][2]);
                pk.w = f2bf(acc[mt][nt][3]);
                *(ushort4*)(Ovt + ((size_t)((b_ * 16 + h) * 64 + idx)) * 2048 + l0) = pk;
            }
        }
    }
}

// ---------------- causal phi-attention + fused RMSNorm ----------------------
// 512 thr = 8 waves; block tile = 256 queries (wave w: 32 q). Pair (7-j, j)
// -> 18 chunks/block. Per 128-key chunk: stage V [64f][128k] (dbuf, swizzled
// src gld_lds, 1 barrier), K frags dense from global (prefetched), QK^T via
// 32x32x16 (S^T), phi in-reg, cvt_pk+permlane32_swap -> PV A-frags in-reg,
// PV B-frags via conflict-free swizzled ds_read_b128.
__global__ __launch_bounds__(512, 2)
void attn_kernel(const u16* __restrict__ Qg, const u16* __restrict__ Kg,
                 const u16* __restrict__ Vt, const u16* __restrict__ gwb,
                 u16* __restrict__ Yn)
{
    __shared__ __attribute__((aligned(16))) u16 Vs[2][8192];   // 2 x 16 KB
    const int t = threadIdx.x, lane = t & 63, w = t >> 6;
    const int la = lane & 31, h = lane >> 5;
    // XCD swizzle: 256 blocks, 8 XCDs -> XCD x serves bh [8x, 8x+8)
    const int pid = blockIdx.y * 4 + blockIdx.x;
    const int lid = (pid & 7) * 32 + (pid >> 3);
    const int bh = lid >> 2;
    const int jj = lid & 3;                      // pair index 0..3
    const int b_ = bh >> 4, hh = bh & 15;
    const u16* Qh = Qg + (size_t)bh * (2048 * 16);
    const u16* Kh = Kg + (size_t)bh * (2048 * 16);
    const u16* Vh = Vt + (size_t)bh * (64 * 2048);
    const float gl0 = bf2f(gwb[la]);
    const float gl1 = bf2f(gwb[32 + la]);
    const f32x16 z16 = {0.f,0.f,0.f,0.f,0.f,0.f,0.f,0.f,
                        0.f,0.f,0.f,0.f,0.f,0.f,0.f,0.f};
    const int vbase0 = (la << 8) | (h << 4);     // V-frag lds byte base (ft=0)
    const int vsw = (la & 7) << 4;               // XOR swizzle bits

    auto stageV = [&](int n0s, int bufsel) {
#pragma unroll
        for (int i = 0; i < 2; ++i) {
            const int slot = i * 512 + t;
            const int fl = slot >> 4;
            const int seg = (slot & 15) ^ (fl & 7);   // pre-swizzled source
            gld16(Vh + (size_t)fl * 2048 + n0s + seg * 8,
                  (u16*)Vs[bufsel] + (size_t)(i * 512 + (w << 6)) * 8);
        }
    };

    for (int pass = 0; pass < 2; ++pass) {
        const int qb = pass ? jj : (7 - jj);     // 256-query tile index
        const int q0 = qb * 256 + w * 32;        // wave's first query
        const int kf = 2 * qb + (w >> 2);        // wave's partial (diag) chunk
        const int wp = w & 3;                    // masked tile within it
        const int nck = 2 * qb + 2;              // chunks 0..nck-1

        const s16x8 bq = *(const s16x8*)(Qh + (size_t)(q0 + la) * 16 + h * 8);
        f32x16 yt0 = z16, yt1 = z16;
        s16x8 ka[4];
        const char* vsc = (const char*)Vs[0];

        auto loadK = [&](s16x8* kk, int kcL) {
#pragma unroll
            for (int kt = 0; kt < 4; ++kt)
                kk[kt] = *(const s16x8*)(Kh + (size_t)(kcL * 128 + kt * 32 + la) * 16 + h * 8);
        };

        auto tile = [&](int kt, auto MASKED) {
            constexpr bool masked = decltype(MASKED)::value;
            f32x16 sv = __builtin_amdgcn_mfma_f32_32x32x16_bf16(ka[kt], bq, z16, 0, 0, 0);
            float p[16];
#pragma unroll
            for (int r = 0; r < 16; ++r) {
                const float s = sv[r];
                float pv = fmaf(s, fmaf(s, 0.03125f, 0.25f), 1.0f);
                if (masked) {
                    const int keyloc = (r & 3) + 8 * (r >> 2) + 4 * h;
                    if (keyloc > la) pv = 0.f;
                }
                p[r] = pv;
            }
#pragma unroll
            for (int ks = 0; ks < 2; ++ks) {
                u32 X0, X1, Y0, Y1;
                asm("v_cvt_pk_bf16_f32 %0, %1, %2" : "=v"(X0) : "v"(p[8*ks+0]), "v"(p[8*ks+1]));
                asm("v_cvt_pk_bf16_f32 %0, %1, %2" : "=v"(X1) : "v"(p[8*ks+2]), "v"(p[8*ks+3]));
                asm("v_cvt_pk_bf16_f32 %0, %1, %2" : "=v"(Y0) : "v"(p[8*ks+4]), "v"(p[8*ks+5]));
                asm("v_cvt_pk_bf16_f32 %0, %1, %2" : "=v"(Y1) : "v"(p[8*ks+6]), "v"(p[8*ks+7]));
                // exchange halves: after swap X holds W0 (lo keys), Y holds W2
                asm("v_permlane32_swap_b32 %0, %1" : "+v"(X0), "+v"(Y0));
                asm("v_permlane32_swap_b32 %0, %1" : "+v"(X1), "+v"(Y1));
                union { uint4 u; s16x8 v; } afu;
                afu.u = (uint4){X0, X1, Y0, Y1};
                const int offb = (kt << 6) | (ks << 5);
                const s16x8 vb0 = *(const s16x8*)(vsc + (((vbase0 + offb)) ^ vsw));
                const s16x8 vb1 = *(const s16x8*)(vsc + (((vbase0 + 8192 + offb)) ^ vsw));
                yt0 = __builtin_amdgcn_mfma_f32_32x32x16_bf16(afu.v, vb0, yt0, 0, 0, 0);
                yt1 = __builtin_amdgcn_mfma_f32_32x32x16_bf16(afu.v, vb1, yt1, 0, 0, 0);
            }
        };

        // prologue: stage chunk 0, preload K(0)
        stageV(0, 0);
        loadK(ka, 0);
        __syncthreads();                         // drains gld_lds

        for (int kc = 0; kc < nck; ++kc) {
            const int cur = kc & 1;
            vsc = (const char*)Vs[cur];
            if (kc + 1 < nck) stageV((kc + 1) * 128, cur ^ 1);
            s16x8 kn[4] = {ka[0], ka[1], ka[2], ka[3]};
            if (kc < kf) loadK(kn, kc + 1);      // prefetch next K frags

            if (kc < kf) {
                tile(0, MaskF{}); tile(1, MaskF{});
                tile(2, MaskF{}); tile(3, MaskF{});
            } else if (kc == kf) {
                if (wp == 0)      { tile(0, MaskT{}); }
                else if (wp == 1) { tile(0, MaskF{}); tile(1, MaskT{}); }
                else if (wp == 2) { tile(0, MaskF{}); tile(1, MaskF{}); tile(2, MaskT{}); }
                else              { tile(0, MaskF{}); tile(1, MaskF{}); tile(2, MaskF{}); tile(3, MaskT{}); }
            }
            __syncthreads();                     // drains vmcnt: next V staged
#pragma unroll
            for (int kt = 0; kt < 4; ++kt) ka[kt] = kn[kt];
        }

        // ---- fused RMSNorm + store yn [b,l,1024] ----
#pragma unroll
        for (int r = 0; r < 16; ++r) {
            float ss = yt0[r] * yt0[r] + yt1[r] * yt1[r];
            ss += __shfl_xor(ss, 1);  ss += __shfl_xor(ss, 2);
            ss += __shfl_xor(ss, 4);  ss += __shfl_xor(ss, 8);
            ss += __shfl_xor(ss, 16);
            const float rmsv = rsqrtf(ss * (1.0f / 64.0f) + 1e-5f);
            const int row = q0 + (r & 3) + 8 * (r >> 2) + 4 * h;
            u16* dst = Yn + ((size_t)(b_ * 2048 + row)) * 1024 + hh * 64;
            dst[la]      = f2bf(yt0[r] * rmsv * gl0);
            dst[32 + la] = f2bf(yt1[r] * rmsv * gl1);
        }
    }
}

// ---------------- kv_state as MFMA GEMM -------------------------------------
// grid (4,64): 4-way key split -> 256 blocks (full GPU). Each block: 8 chunks.
__global__ __launch_bounds__(256)
void kv_mfma_kernel(const u16* __restrict__ Kg, const u16* __restrict__ Vt,
                    float* __restrict__ kvpart)
{
    __shared__ __attribute__((aligned(16))) float kS[64][20];
    __shared__ __attribute__((aligned(16))) float kT[64][20];
    __shared__ __attribute__((aligned(16))) u16 KFs[288][72];
    __shared__ __attribute__((aligned(16))) u16 Vs[64][72];
    const int t = threadIdx.x, lane = t & 63, w = t >> 6;
    const int c = lane & 15, qd = lane >> 4;
    const int ns = blockIdx.x, bh = blockIdx.y;
    const u16* Kh  = Kg + (size_t)bh * 2048 * 16;
    const u16* Vth = Vt + (size_t)bh * 64 * 2048;

    int i2a, j2a, i2b = 18, j2b = 18;
    {
        const int dd = t;
        if (dd == 0)      { i2a = 16; j2a = 17; }
        else if (dd < 17) { i2a = dd - 1; j2a = 16; }
        else              { i2a = (dd - 17) >> 4; j2a = (dd - 17) & 15; }
        if (t < 32) {
            const int d2 = 256 + t;
            if (d2 < 273) { i2b = (d2 - 17) >> 4; j2b = (d2 - 17) & 15; }
        }
    }

    f32x4 acc[4][5];
#pragma unroll
    for (int mt = 0; mt < 4; ++mt)
#pragma unroll
        for (int j = 0; j < 5; ++j) acc[mt][j] = (f32x4){0.f, 0.f, 0.f, 0.f};

    for (int ch = 0; ch < 8; ++ch) {
        const int n0 = ns * 512 + ch * 64;
        __syncthreads();
        if (t < 128) {
            const int row = t >> 1, half = t & 1;
            uint4 kv = *(const uint4*)(Kh + (size_t)(n0 + row) * 16 + half * 8);
            const u16* ke = (const u16*)&kv;
#pragma unroll
            for (int e = 0; e < 8; ++e) {
                const float f = bf2f(ke[e]);
                kS[row][half * 8 + e] = f;
                kT[row][half * 8 + e] = f * 0.17677669529663687f;
            }
        } else if (t < 192) {
            const int row = t - 128;
            kS[row][16] = 1.f;  kS[row][17] = 1.f;  kS[row][18] = 0.f;
            kT[row][16] = 0.5f; kT[row][17] = 1.f;  kT[row][18] = 0.f;
        }
        // stage V^T from vt: conflict-free b128
#pragma unroll
        for (int i = 0; i < 2; ++i) {
            const int lin = i * 256 + t;
            const int f = lin >> 3, seg = lin & 7;
            *(uint4*)&Vs[f][seg * 8] =
                *(const uint4*)(Vth + (size_t)f * 2048 + n0 + seg * 8);
        }
        __syncthreads();
        {
            unsigned int* dst = (unsigned int*)&KFs[t][0];
#pragma unroll 8
            for (int i = 0; i < 32; ++i) {
                const float v0 = kS[2 * i][i2a]     * kT[2 * i][j2a];
                const float v1 = kS[2 * i + 1][i2a] * kT[2 * i + 1][j2a];
                dst[i] = (unsigned int)f2bf(v0) | ((unsigned int)f2bf(v1) << 16);
            }
            if (t < 32) {
                unsigned int* dst2 = (unsigned int*)&KFs[256 + t][0];
#pragma unroll 8
                for (int i = 0; i < 32; ++i) {
                    const float v0 = kS[2 * i][i2b]     * kT[2 * i][j2b];
                    const float v1 = kS[2 * i + 1][i2b] * kT[2 * i + 1][j2b];
                    dst2[i] = (unsigned int)f2bf(v0) | ((unsigned int)f2bf(v1) << 16);
                }
            }
        }
        __syncthreads();
#pragma unroll
        for (int kt = 0; kt < 2; ++kt) {
            s16x8 va[4];
#pragma unroll
            for (int mt = 0; mt < 4; ++mt)
                va[mt] = *(const s16x8*)&Vs[mt * 16 + c][kt * 32 + qd * 8];
#pragma unroll
            for (int j = 0; j < 5; ++j) {
                const int dt = w + 4 * j;
                if (dt < 18) {
                    s16x8 vb = *(const s16x8*)&KFs[dt * 16 + c][kt * 32 + qd * 8];
#pragma unroll
                    for (int mt = 0; mt < 4; ++mt)
                        acc[mt][j] = __builtin_amdgcn_mfma_f32_16x16x32_bf16(va[mt], vb, acc[mt][j], 0, 0, 0);
                }
            }
        }
    }

    float* base = kvpart + ((size_t)(ns * 64 + bh) * 64) * 273;
#pragma unroll
    for (int j = 0; j < 5; ++j) {
        const int dt = w + 4 * j;
        if (dt >= 18) continue;
        const int dd = dt * 16 + c;
        if (dd >= 273) continue;
#pragma unroll
        for (int mt = 0; mt < 4; ++mt)
#pragma unroll
            for (int r = 0; r < 4; ++r) {
                const int f = mt * 16 + qd * 4 + r;
                base[f * 273 + dd] = acc[mt][j][r];
            }
    }
}

__global__ __launch_bounds__(256)
void kv_fin_kernel(const float* __restrict__ kvpart, float* __restrict__ o)
{
    const int i = blockIdx.x * 256 + threadIdx.x;
    const int S = 64 * 64 * 273;
    if (i < S)
        o[i] = kvpart[i] + kvpart[i + S] + kvpart[i + 2 * S] + kvpart[i + 3 * S];
}

// ---------------------------------------------------------------------------
extern "C" void kernel_launch(void* const* d_in, const int* in_sizes, int n_in,
                              void* d_out, int out_size, void* d_ws, size_t ws_size,
                              hipStream_t stream)
{
    const void* H  = d_in[0];
    const void* Wq = d_in[1];
    const void* Wk = d_in[2];
    const void* Wv = d_in[3];
    const void* Wo = d_in[4];
    const void* gw = d_in[5];
    float* outf = (float*)d_out;

    char* ws = (char*)d_ws;
    const size_t M = 1 << 20;
    u16*   Hb    = (u16*)(ws);                          // 16 MiB (reused as yn)
    u16*   Wqb   = (u16*)(ws + 16 * M);
    u16*   Wkb   = (u16*)(ws + 16 * M + 512 * 1024);
    u16*   Wvb   = (u16*)(ws + 17 * M);
    u16*   Wob   = (u16*)(ws + 19 * M);
    u16*   gwb   = (u16*)(ws + 21 * M);
    int*   flag  = (int*)(ws + 21 * M + 4096);
    u16*   q     = (u16*)(ws + 22 * M);                 // 4 MiB
    u16*   k     = (u16*)(ws + 26 * M);                 // 4 MiB
    u16*   vt    = (u16*)(ws + 30 * M);                 // 16 MiB [b,h,64,l]
    float* kvpart= (float*)(ws + 46 * M);               // 4 x 4.27 MiB slabs
    u16*   yn    = Hb;                                  // reuse after gemm0

    detect_kernel<<<1, 64, 0, stream>>>((const unsigned int*)H, flag);
    cvt_kernel<<<(in_sizes[0] + 255) / 256, 256, 0, stream>>>(H,  Hb,  in_sizes[0], flag);
    cvt_kernel<<<(in_sizes[1] + 255) / 256, 256, 0, stream>>>(Wq, Wqb, in_sizes[1], flag);
    cvt_kernel<<<(in_sizes[2] + 255) / 256, 256, 0, stream>>>(Wk, Wkb, in_sizes[2], flag);
    cvt_kernel<<<(in_sizes[3] + 255) / 256, 256, 0, stream>>>(Wv, Wvb, in_sizes[3], flag);
    cvt_kernel<<<(in_sizes[4] + 255) / 256, 256, 0, stream>>>(Wo, Wob, in_sizes[4], flag);
    cvt_kernel<<<1, 256, 0, stream>>>(gw, gwb, in_sizes[5], flag);

    gemm_nt<0><<<dim3(12, 64), 256, 0, stream>>>(Hb, Wqb, Wkb, Wvb, q, k, vt, nullptr);
    attn_kernel<<<dim3(4, 64), 512, 0, stream>>>(q, k, vt, gwb, yn);
    kv_mfma_kernel<<<dim3(4, 64), 256, 0, stream>>>(k, vt, kvpart);
    kv_fin_kernel<<<4368, 256, 0, stream>>>(kvpart, outf + (size_t)8388608);
    gemm_nt<1><<<dim3(8, 64), 256, 0, stream>>>(yn, Wob, nullptr, nullptr,
                                                nullptr, nullptr, nullptr, outf);
}